// Round 7
// baseline (408.953 us; speedup 1.0000x reference)
//
#include <hip/hip_runtime.h>

// AdjointODE: h += dt * ( tanh(h@W1+b1) @ W2 + b2 ), 50 Euler steps.
// BATCH=32768, DIM=128, HID=256.
// ROUND 7: 16x16x32 MFMA, TWO independent 16-row groups per wave (32 rows
// total, grid stays 256x256 = 1 wave/SIMD). Short dep chains (mm1 = 4
// independent 4-chains/pair vs round-6's single 9-chain) + 2x group ILP in
// every stage, all inside one loop body. Weight A-frags read once, feed both
// groups. K-permutation sigma (b -> 8*((b&15)>>2) + 4*(b>>4) + (b&3)) applied
// to weight storage makes C-layout register order == B-frag lane order: state
// packs stay pure consecutive-register pk2, zero cross-lane ops.
// b1 folds in as f32 accumulator init (saves 32 MFMAs/step); tanh scale
// 2/ln2 pre-folded into W1/b1 at staging (saves 128 v_mul/step).
// Outer loops unroll-1 (round-3 lesson: unroll -> 256-VGPR spill; canary =
// FETCH ~9.3 MB / WRITE ~16.4 MB).

typedef __attribute__((ext_vector_type(8))) short short8;
typedef __attribute__((ext_vector_type(4))) float float4v;
typedef __attribute__((ext_vector_type(4))) int int4v;

union FB { int4v i; short8 s; };

#define W1S 136  // shorts/row: 128 K + 8 pad (272 B, 16B-aligned)
#define W2S 296  // shorts/row: 256 K + 32 bias-block + 8 pad (592 B)
#define W2_OFF (256 * W1S)            // 34816 shorts
#define B1_OFF (W2_OFF + 128 * W2S)   // 72704 shorts (byte 145408, 16B-aligned)
#define DT_OFF (B1_OFF + 512)         // b1f = 256 f32
#define LDS_SHORTS (DT_OFF + 128)     // 73344 shorts = 146688 B

#define TSCALE 2.8853900817779268f  // 2/ln2: tanh(x) = 1 - 2/(exp2(x*TSCALE)+1)

__device__ __forceinline__ unsigned rne2(float x) {
  unsigned u = __float_as_uint(x);
  return u + 0x7fffu + ((u >> 16) & 1u);
}
__device__ __forceinline__ unsigned short bf16s(float x) {
  return (unsigned short)(rne2(x) >> 16);
}

#if __has_builtin(__builtin_amdgcn_cvt_pk_bf16_f32)
__device__ __forceinline__ int pk2(float lo, float hi) {
  return __builtin_bit_cast(int, __builtin_amdgcn_cvt_pk_bf16_f32(lo, hi));
}
#else
__device__ __forceinline__ int pk2(float lo, float hi) {
  return (int)__builtin_amdgcn_perm(rne2(hi), rne2(lo), 0x07060302u);
}
#endif

// sigma: storage position of logical K offset b within its 32-block.
// Makes B-frag lane order (k = 8q + j) equal the C-layout register order
// (16-block t, elem 4q + r): j<4 <-> t even r=j, j>=4 <-> t odd r=j-4.
__device__ __forceinline__ int swz32(int d) {
  int b = d & 31;
  return (d & ~31) | (((b >> 2) & 3) << 3) | ((b >> 4) << 2) | (b & 3);
}

// B-frag for one 32-K chunk from two C-layout float4 tiles (even, odd).
__device__ __forceinline__ int4v packfrag(float4v e, float4v o) {
  int4v f;
  f.x = pk2(e.x, e.y);
  f.y = pk2(e.z, e.w);
  f.z = pk2(o.x, o.y);
  f.w = pk2(o.z, o.w);
  return f;
}

#define MFMA16(a, b, c) __builtin_amdgcn_mfma_f32_16x16x32_bf16(a, b, c, 0, 0, 0)

extern "C" __global__ __launch_bounds__(256)
void ode_kernel(const float* __restrict__ inp, const float* __restrict__ ts,
                const float* __restrict__ W1, const float* __restrict__ b1,
                const float* __restrict__ W2, const float* __restrict__ b2,
                float* __restrict__ out) {
  __shared__ __align__(16) unsigned short lds[LDS_SHORTS];
  unsigned short* w1t = lds;           // w1t[n=hid][swz32(k=dim)], pre-scaled by TSCALE
  unsigned short* w2t = lds + W2_OFF;  // w2t[d=dim][swz32(k2=hid); 256->b2, 257..287->0]
  float* b1f = (float*)(lds + B1_OFF); // b1 * TSCALE, f32
  float* dtf = (float*)(lds + DT_OFF);

  const int tid = threadIdx.x;
  const int lane = tid & 63, wave = tid >> 6;
  const int ln = lane & 15;  // free-dim index (batch row / hid / dim)
  const int q = lane >> 4;   // quad
  const int rowb = blockIdx.x * 128 + wave * 32;

  // ---- stage W1 (transposed + sigma-swizzled + TSCALE-folded) ----
  {
    const int n = tid;  // hid 0..255
    unsigned short* dst = &w1t[n * W1S];
    #pragma unroll 4
    for (int k = 0; k < 128; k++)
      dst[swz32(k)] = bf16s(W1[k * 256 + n] * TSCALE);
    dst[128] = 0; dst[129] = 0; dst[130] = 0; dst[131] = 0;
    dst[132] = 0; dst[133] = 0; dst[134] = 0; dst[135] = 0;
  }
  // ---- stage W2 (transposed + sigma-swizzled; k2=256 -> b2, 257..287 -> 0) ----
  {
    const int d = tid >> 1, part = tid & 1;
    unsigned short* dst = &w2t[d * W2S];
    for (int k2 = part * 144; k2 < part * 144 + 144; k2++) {
      unsigned short v;
      if (k2 < 256) v = bf16s(W2[k2 * 128 + d]);
      else if (k2 == 256) v = bf16s(b2[d]);
      else v = 0;
      dst[swz32(k2)] = v;
    }
    if (part) { dst[288] = 0; dst[289] = 0; dst[290] = 0; dst[291] = 0;
                dst[292] = 0; dst[293] = 0; dst[294] = 0; dst[295] = 0; }
  }
  if (tid < 256) b1f[tid] = b1[tid] * TSCALE;
  if (tid < 50) dtf[tid] = ts[tid + 1] - ts[tid];

  // ---- load h: 16x16 C-layout, two row-groups u ----
  // h4[u][tb]: row = rowb + u*16 + ln, dims tb*16 + q*4 + {0..3}
  float4v h4[2][8];
  #pragma unroll
  for (int u = 0; u < 2; u++)
    #pragma unroll
    for (int tb = 0; tb < 8; tb++)
      h4[u][tb] = *(const float4v*)&inp[(rowb + u * 16 + ln) * 128 + tb * 16 + q * 4];

  __syncthreads();  // the only barrier

  #pragma unroll 1
  for (int s = 0; s < 50; s++) {
    const float dt = dtf[s];
    const float m2dt = -2.0f * dt;

    // ---- state -> 4 B-frags per group (pure register packing) ----
    FB hb[2][4];
    #pragma unroll
    for (int u = 0; u < 2; u++)
      #pragma unroll
      for (int kc = 0; kc < 4; kc++)
        hb[u][kc].i = packfrag(h4[u][2 * kc], h4[u][2 * kc + 1]);

    // ---- mm2 bias chunk: h += [dt,0,..] @ [b2-row;0..] ----
    {
      FB dfr;
      dfr.i = (int4v){q == 0 ? pk2(dt, 0.0f) : 0, 0, 0, 0};
      #pragma unroll
      for (int tb = 0; tb < 8; tb++) {
        FB w;
        w.s = *(const short8*)&w2t[(tb * 16 + ln) * W2S + 256 + q * 8];
        h4[0][tb] = MFMA16(w.s, dfr.s, h4[0][tb]);
        h4[1][tb] = MFMA16(w.s, dfr.s, h4[1][tb]);
      }
    }

    // ---- 8 hid-pairs (32 hid each): mm1 -> tanh -> mm2 ----
    #pragma unroll 1
    for (int p = 0; p < 8; p++) {
      const int nt0 = 2 * p, nt1 = 2 * p + 1;
      // A-frags for the two hid-tiles (shared by both row-groups)
      FB wA[4], wB[4];
      const unsigned short* wrA = &w1t[(nt0 * 16 + ln) * W1S + q * 8];
      const unsigned short* wrB = &w1t[(nt1 * 16 + ln) * W1S + q * 8];
      #pragma unroll
      for (int c = 0; c < 4; c++) {
        wA[c].s = *(const short8*)&wrA[c * 32];
        wB[c].s = *(const short8*)&wrB[c * 32];
      }
      // g init = b1 (pre-scaled), broadcast over batch cols
      float4v bi0 = *(const float4v*)&b1f[nt0 * 16 + q * 4];
      float4v bi1 = *(const float4v*)&b1f[nt1 * 16 + q * 4];
      float4v g00 = bi0, g01 = bi1, g10 = bi0, g11 = bi1;
      #pragma unroll
      for (int c = 0; c < 4; c++) {  // 4 independent 4-chains
        g00 = MFMA16(wA[c].s, hb[0][c].s, g00);
        g10 = MFMA16(wA[c].s, hb[1][c].s, g10);
        g01 = MFMA16(wB[c].s, hb[0][c].s, g01);
        g11 = MFMA16(wB[c].s, hb[1][c].s, g11);
      }

      // W2 frags for this 32-K chunk (issued before tanh; latency hides under it)
      FB w2f[8];
      #pragma unroll
      for (int tb = 0; tb < 8; tb++)
        w2f[tb].s = *(const short8*)&w2t[(tb * 16 + ln) * W2S + p * 32 + q * 8];

      // act = dt*tanh: a = dt - 2dt * rcp(exp2(g) + 1)   [g pre-scaled]
      float4v a00, a01, a10, a11;
      #pragma unroll
      for (int r = 0; r < 4; r++) {
        a00[r] = fmaf(__builtin_amdgcn_rcpf(__builtin_amdgcn_exp2f(g00[r]) + 1.0f), m2dt, dt);
        a10[r] = fmaf(__builtin_amdgcn_rcpf(__builtin_amdgcn_exp2f(g10[r]) + 1.0f), m2dt, dt);
        a01[r] = fmaf(__builtin_amdgcn_rcpf(__builtin_amdgcn_exp2f(g01[r]) + 1.0f), m2dt, dt);
        a11[r] = fmaf(__builtin_amdgcn_rcpf(__builtin_amdgcn_exp2f(g11[r]) + 1.0f), m2dt, dt);
      }
      FB af0, af1;
      af0.i = packfrag(a00, a01);
      af1.i = packfrag(a10, a11);

      // mm2: h += act-chunk @ W2-chunk (16 independent accumulator chains)
      #pragma unroll
      for (int tb = 0; tb < 8; tb++) {
        h4[0][tb] = MFMA16(w2f[tb].s, af0.s, h4[0][tb]);
        h4[1][tb] = MFMA16(w2f[tb].s, af1.s, h4[1][tb]);
      }
    }
  }

  // ---- store ----
  #pragma unroll
  for (int u = 0; u < 2; u++)
    #pragma unroll
    for (int tb = 0; tb < 8; tb++)
      *(float4v*)&out[(rowb + u * 16 + ln) * 128 + tb * 16 + q * 4] = h4[u][tb];
}

extern "C" void kernel_launch(void* const* d_in, const int* in_sizes, int n_in,
                              void* d_out, int out_size, void* d_ws, size_t ws_size,
                              hipStream_t stream) {
  const float* inp = (const float*)d_in[0];
  const float* ts  = (const float*)d_in[1];
  const float* W1  = (const float*)d_in[2];
  const float* b1  = (const float*)d_in[3];
  const float* W2  = (const float*)d_in[4];
  const float* b2  = (const float*)d_in[5];
  hipLaunchKernelGGL(ode_kernel, dim3(256), dim3(256), 0, stream,
                     inp, ts, W1, b1, W2, b2, (float*)d_out);
}

// Round 8
// 320.271 us; speedup vs baseline: 1.2769x; 1.2769x over previous
//
#include <hip/hip_runtime.h>

// AdjointODE: h += dt * ( tanh(h@W1+b1) @ W2 + b2 ), 50 Euler steps.
// BATCH=32768, DIM=128, HID=256.
// ROUND 8: TLP. 256 blocks x 512 threads = 8 waves/block = 2 waves/SIMD
// (rounds 5-7 proved 1 wave/SIMD is dependency-latency-bound: three ILP
// restructures each predicted -40% and delivered -3..+6%; m114 says
// co-resident waves overlap fully). Wave owns 16 rows; h fp32-resident.
// 16x16x32 MFMA, A=weights (LDS, sigma-K-swizzled), B=state (pure-register
// pk2 packing, zero cross-lane ops). Strides back to ==12 mod 32 dwords
// (round-7's 136-short stride caused 2.7e7 bank-conflict cycles; round-6's
// 152/280 measured clean). Bias b2 via VALU fma from regs (bias-MFMA chunk
// dropped); b1 folded as f32 accumulator init; tanh scale pre-folded in W1/b1.
// Plain __launch_bounds__(512): the (512,2) form capped VGPR at 128 in round
// 2 -> 5.3 GB spill. Outer loops unroll-1 (round-3 lesson). Spill canary:
// FETCH ~9.3 MB / WRITE ~16.4 MB.

typedef __attribute__((ext_vector_type(8))) short short8;
typedef __attribute__((ext_vector_type(4))) float float4v;
typedef __attribute__((ext_vector_type(4))) int int4v;

union FB { int4v i; short8 s; };

#define W1S 152  // shorts/row: 128 K + 24 pad; 76 dw == 12 mod 32 (conflict-clean)
#define W2S 280  // shorts/row: 256 K + 24 pad; 140 dw == 12 mod 32
#define W2_OFF (256 * W1S)            // 38912 shorts
#define B1_OFF (W2_OFF + 128 * W2S)   // 74752 shorts (byte 149504, 16B-aligned)
#define DT_OFF (B1_OFF + 512)         // b1f = 256 f32
#define LDS_SHORTS (DT_OFF + 128)     // 75392 shorts = 150784 B (1 block/CU)

#define TSCALE 2.8853900817779268f  // 2/ln2: tanh(x) = 1 - 2/(exp2(x*TSCALE)+1)

__device__ __forceinline__ unsigned rne2(float x) {
  unsigned u = __float_as_uint(x);
  return u + 0x7fffu + ((u >> 16) & 1u);
}
__device__ __forceinline__ unsigned short bf16s(float x) {
  return (unsigned short)(rne2(x) >> 16);
}

#if __has_builtin(__builtin_amdgcn_cvt_pk_bf16_f32)
__device__ __forceinline__ int pk2(float lo, float hi) {
  return __builtin_bit_cast(int, __builtin_amdgcn_cvt_pk_bf16_f32(lo, hi));
}
#else
__device__ __forceinline__ int pk2(float lo, float hi) {
  return (int)__builtin_amdgcn_perm(rne2(hi), rne2(lo), 0x07060302u);
}
#endif

// sigma: storage position of logical K offset within its 32-block, making
// B-frag lane order (k = 8q + j) equal the C-layout register order.
__device__ __forceinline__ int swz32(int d) {
  int b = d & 31;
  return (d & ~31) | (((b >> 2) & 3) << 3) | ((b >> 4) << 2) | (b & 3);
}

// B-frag for one 32-K chunk from two C-layout float4 tiles (even, odd).
__device__ __forceinline__ int4v packfrag(float4v e, float4v o) {
  int4v f;
  f.x = pk2(e.x, e.y);
  f.y = pk2(e.z, e.w);
  f.z = pk2(o.x, o.y);
  f.w = pk2(o.z, o.w);
  return f;
}

#define MFMA16(a, b, c) __builtin_amdgcn_mfma_f32_16x16x32_bf16(a, b, c, 0, 0, 0)

extern "C" __global__ __launch_bounds__(512)
void ode_kernel(const float* __restrict__ inp, const float* __restrict__ ts,
                const float* __restrict__ W1, const float* __restrict__ b1,
                const float* __restrict__ W2, const float* __restrict__ b2,
                float* __restrict__ out) {
  __shared__ __align__(16) unsigned short lds[LDS_SHORTS];
  unsigned short* w1t = lds;           // w1t[n=hid][swz32(k=dim)], TSCALE-folded
  unsigned short* w2t = lds + W2_OFF;  // w2t[d=dim][swz32(k2=hid)]
  float* b1f = (float*)(lds + B1_OFF); // b1 * TSCALE, f32
  float* dtf = (float*)(lds + DT_OFF);

  const int tid = threadIdx.x;
  const int lane = tid & 63, wave = tid >> 6;
  const int ln = lane & 15;  // batch-row within wave's 16
  const int q = lane >> 4;   // quad
  const int row = blockIdx.x * 128 + wave * 16 + ln;

  // ---- stage W1 (transposed + sigma + TSCALE); 2 threads per hid row ----
  {
    const int n = tid >> 1, part = tid & 1;
    unsigned short* dst = &w1t[n * W1S];
    #pragma unroll 4
    for (int k = part * 64; k < part * 64 + 64; k++)
      dst[swz32(k)] = bf16s(W1[k * 256 + n] * TSCALE);
    if (part) {
      #pragma unroll
      for (int k = 128; k < 152; k++) dst[k] = 0;
    }
  }
  // ---- stage W2 (transposed + sigma); 4 threads per dim row ----
  {
    const int d = tid >> 2, part = tid & 3;
    unsigned short* dst = &w2t[d * W2S];
    #pragma unroll 4
    for (int k2 = part * 64; k2 < part * 64 + 64; k2++)
      dst[swz32(k2)] = bf16s(W2[k2 * 128 + d]);
    if (part == 3) {
      #pragma unroll
      for (int k2 = 256; k2 < 280; k2++) dst[k2] = 0;
    }
  }
  if (tid < 256) b1f[tid] = b1[tid] * TSCALE;
  if (tid < 50) dtf[tid] = ts[tid + 1] - ts[tid];

  // ---- b2 resident per-lane (C-layout columns) ----
  float4v b2v[8];
  #pragma unroll
  for (int tb = 0; tb < 8; tb++)
    b2v[tb] = *(const float4v*)&b2[tb * 16 + q * 4];

  // ---- load h: 16x16 C-layout. h4[tb][r] = h[row][tb*16 + q*4 + r] ----
  float4v h4[8];
  #pragma unroll
  for (int tb = 0; tb < 8; tb++)
    h4[tb] = *(const float4v*)&inp[row * 128 + tb * 16 + q * 4];

  __syncthreads();  // the only barrier

  #pragma unroll 1
  for (int s = 0; s < 50; s++) {
    const float dt = dtf[s];
    const float m2dt = -2.0f * dt;

    // ---- state -> 4 B-frags (pure register packing) ----
    FB hb[4];
    #pragma unroll
    for (int kc = 0; kc < 4; kc++)
      hb[kc].i = packfrag(h4[2 * kc], h4[2 * kc + 1]);

    // ---- 8 hid-pairs (32 hid each): mm1 -> tanh -> mm2 ----
    #pragma unroll 1
    for (int p = 0; p < 8; p++) {
      const int nt0 = 2 * p, nt1 = 2 * p + 1;
      FB wA[4], wB[4];
      const unsigned short* wrA = &w1t[(nt0 * 16 + ln) * W1S + q * 8];
      const unsigned short* wrB = &w1t[(nt1 * 16 + ln) * W1S + q * 8];
      #pragma unroll
      for (int c = 0; c < 4; c++) {
        wA[c].s = *(const short8*)&wrA[c * 32];
        wB[c].s = *(const short8*)&wrB[c * 32];
      }
      // g init = b1 (pre-scaled), two independent 4-chains
      float4v g0 = *(const float4v*)&b1f[nt0 * 16 + q * 4];
      float4v g1 = *(const float4v*)&b1f[nt1 * 16 + q * 4];
      #pragma unroll
      for (int c = 0; c < 4; c++) {
        g0 = MFMA16(wA[c].s, hb[c].s, g0);
        g1 = MFMA16(wB[c].s, hb[c].s, g1);
      }

      // W2 frags for this 32-K chunk (issued before tanh)
      FB w2f[8];
      #pragma unroll
      for (int tb = 0; tb < 8; tb++)
        w2f[tb].s = *(const short8*)&w2t[(tb * 16 + ln) * W2S + p * 32 + q * 8];

      // act = dt*tanh: a = dt - 2dt * rcp(exp2(g) + 1)   [g pre-scaled]
      float4v a0, a1;
      #pragma unroll
      for (int r = 0; r < 4; r++) {
        a0[r] = fmaf(__builtin_amdgcn_rcpf(__builtin_amdgcn_exp2f(g0[r]) + 1.0f), m2dt, dt);
        a1[r] = fmaf(__builtin_amdgcn_rcpf(__builtin_amdgcn_exp2f(g1[r]) + 1.0f), m2dt, dt);
      }
      FB af;
      af.i = packfrag(a0, a1);

      // mm2: h += act-chunk @ W2-chunk (8 independent accumulator chains)
      #pragma unroll
      for (int tb = 0; tb < 8; tb++)
        h4[tb] = MFMA16(w2f[tb].s, af.s, h4[tb]);
    }

    // ---- h += dt * b2 ----
    #pragma unroll
    for (int tb = 0; tb < 8; tb++)
      #pragma unroll
      for (int r = 0; r < 4; r++)
        h4[tb][r] = fmaf(dt, b2v[tb][r], h4[tb][r]);
  }

  // ---- store ----
  #pragma unroll
  for (int tb = 0; tb < 8; tb++)
    *(float4v*)&out[row * 128 + tb * 16 + q * 4] = h4[tb];
}

extern "C" void kernel_launch(void* const* d_in, const int* in_sizes, int n_in,
                              void* d_out, int out_size, void* d_ws, size_t ws_size,
                              hipStream_t stream) {
  const float* inp = (const float*)d_in[0];
  const float* ts  = (const float*)d_in[1];
  const float* W1  = (const float*)d_in[2];
  const float* b1  = (const float*)d_in[3];
  const float* W2  = (const float*)d_in[4];
  const float* b2  = (const float*)d_in[5];
  hipLaunchKernelGGL(ode_kernel, dim3(256), dim3(512), 0, stream,
                     inp, ts, W1, b1, W2, b2, (float*)d_out);
}

// Round 9
// 316.563 us; speedup vs baseline: 1.2919x; 1.0117x over previous
//
#include <hip/hip_runtime.h>

// AdjointODE: h += dt * ( tanh(h@W1+b1) @ W2 + b2 ), 50 Euler steps.
// BATCH=32768, DIM=128, HID=256.
// ROUND 9: FRAGMENT-LINEAR weight LDS. Weights stored as MFMA A-fragments:
// 1 KB per (tile, K-chunk) frag, lane's 16 B at frag_base + lane*16.
//  - staging: 16 ds_write_b128/thread, wave-contiguous, conflict-free
//    (r8's 64k scalar swizzled ds_write_b16/block caused 5.4e7 conflict
//    cycles ~= 88 us of pre-loop LDS serialization);
//  - reads: ds_read_b128 at base + lane*16 + fid*1024 (m97 pattern,
//    conflict-free, frag offsets fold into immediates -> less addr VALU).
// Frag contents identical to r8's swz32 layout => bit-identical math.
// Everything else = r8: 256x512 (2 waves/SIMD, the round-8 TLP win), wave
// owns 16 rows, h fp32-resident, sigma-matched pure-register pk2 packing,
// b1 as accumulator init (TSCALE-folded), b2 via VALU fma.
// Outer loops unroll-1 (round-3 lesson). Spill canary: FETCH ~9.3 MB.

typedef __attribute__((ext_vector_type(8))) short short8;
typedef __attribute__((ext_vector_type(4))) float float4v;
typedef __attribute__((ext_vector_type(4))) int int4v;

union FB { int4v i; short8 s; };

// LDS map (bytes)
#define W1F_OFF 0        // 64 frags (nt*4+c) x 1 KB = 64 KB
#define W2F_OFF 65536    // 64 frags (p*8+tb) x 1 KB = 64 KB
#define B1_OFF  131072   // f32[256] (TSCALE-folded b1)
#define DT_OFF  132096   // f32[64]
#define LDS_BYTES 132352

#define TSCALE 2.8853900817779268f  // 2/ln2: tanh(x) = 1 - 2/(exp2(x*TSCALE)+1)

__device__ __forceinline__ unsigned rne2(float x) {
  unsigned u = __float_as_uint(x);
  return u + 0x7fffu + ((u >> 16) & 1u);
}

#if __has_builtin(__builtin_amdgcn_cvt_pk_bf16_f32)
__device__ __forceinline__ int pk2(float lo, float hi) {
  return __builtin_bit_cast(int, __builtin_amdgcn_cvt_pk_bf16_f32(lo, hi));
}
#else
__device__ __forceinline__ int pk2(float lo, float hi) {
  return (int)__builtin_amdgcn_perm(rne2(hi), rne2(lo), 0x07060302u);
}
#endif

// B-frag for one 32-K chunk from two C-layout float4 tiles (even, odd).
// Frag short j (j<4): logical K offset q*4+j; (j>=4): 16+q*4+(j-4).
__device__ __forceinline__ int4v packfrag(float4v e, float4v o) {
  int4v f;
  f.x = pk2(e.x, e.y);
  f.y = pk2(e.z, e.w);
  f.z = pk2(o.x, o.y);
  f.w = pk2(o.z, o.w);
  return f;
}

#define MFMA16(a, b, c) __builtin_amdgcn_mfma_f32_16x16x32_bf16(a, b, c, 0, 0, 0)

extern "C" __global__ __launch_bounds__(512)
void ode_kernel(const float* __restrict__ inp, const float* __restrict__ ts,
                const float* __restrict__ W1, const float* __restrict__ b1,
                const float* __restrict__ W2, const float* __restrict__ b2,
                float* __restrict__ out) {
  __shared__ __align__(16) char ldsb[LDS_BYTES];
  float* b1f = (float*)(ldsb + B1_OFF);
  float* dtf = (float*)(ldsb + DT_OFF);

  const int tid = threadIdx.x;
  const int lane = tid & 63, wave = tid >> 6;
  const int ln = lane & 15;  // batch-row within wave's 16
  const int q = lane >> 4;   // quad
  const int row = blockIdx.x * 128 + wave * 16 + ln;

  // ---- stage W1 frags: pair pi = (fid=nt*4+c)*64 + L; wave covers one frag ----
  #pragma unroll 1
  for (int it = 0; it < 8; it++) {
    const int pi = it * 512 + tid;  // [0, 4096)
    const int fid = pi >> 6, L = pi & 63;
    const int nt = fid >> 2, c = fid & 3;
    const int lf = L & 15, qf = L >> 4;
    const int n = nt * 16 + lf;            // hid index (A-frag m-row)
    const int kb = c * 32 + qf * 4;        // logical dim base
    float v0 = W1[(kb + 0) * 256 + n] * TSCALE;
    float v1 = W1[(kb + 1) * 256 + n] * TSCALE;
    float v2 = W1[(kb + 2) * 256 + n] * TSCALE;
    float v3 = W1[(kb + 3) * 256 + n] * TSCALE;
    float v4 = W1[(kb + 16) * 256 + n] * TSCALE;
    float v5 = W1[(kb + 17) * 256 + n] * TSCALE;
    float v6 = W1[(kb + 18) * 256 + n] * TSCALE;
    float v7 = W1[(kb + 19) * 256 + n] * TSCALE;
    int4v d = {pk2(v0, v1), pk2(v2, v3), pk2(v4, v5), pk2(v6, v7)};
    *(int4v*)(ldsb + W1F_OFF + pi * 16) = d;
  }
  // ---- stage W2 frags: fid = p*8 + tb ----
  #pragma unroll 1
  for (int it = 0; it < 8; it++) {
    const int pi = it * 512 + tid;
    const int fid = pi >> 6, L = pi & 63;
    const int p = fid >> 3, tb = fid & 7;
    const int lf = L & 15, qf = L >> 4;
    const int d_out = tb * 16 + lf;        // output-dim (A-frag m-row)
    const int kb = p * 32 + qf * 4;        // logical hid base
    float v0 = W2[(kb + 0) * 128 + d_out];
    float v1 = W2[(kb + 1) * 128 + d_out];
    float v2 = W2[(kb + 2) * 128 + d_out];
    float v3 = W2[(kb + 3) * 128 + d_out];
    float v4 = W2[(kb + 16) * 128 + d_out];
    float v5 = W2[(kb + 17) * 128 + d_out];
    float v6 = W2[(kb + 18) * 128 + d_out];
    float v7 = W2[(kb + 19) * 128 + d_out];
    int4v d = {pk2(v0, v1), pk2(v2, v3), pk2(v4, v5), pk2(v6, v7)};
    *(int4v*)(ldsb + W2F_OFF + pi * 16) = d;
  }
  if (tid < 256) b1f[tid] = b1[tid] * TSCALE;
  if (tid < 50) dtf[tid] = ts[tid + 1] - ts[tid];

  // ---- b2 resident per-lane (C-layout columns) ----
  float4v b2v[8];
  #pragma unroll
  for (int tb = 0; tb < 8; tb++)
    b2v[tb] = *(const float4v*)&b2[tb * 16 + q * 4];

  // ---- load h: 16x16 C-layout. h4[tb][r] = h[row][tb*16 + q*4 + r] ----
  float4v h4[8];
  #pragma unroll
  for (int tb = 0; tb < 8; tb++)
    h4[tb] = *(const float4v*)&inp[row * 128 + tb * 16 + q * 4];

  __syncthreads();  // the only barrier

  // per-lane frag base pointers (reads: base + fid*64 int4vs + immediate)
  const int4v* w1f = (const int4v*)(ldsb + W1F_OFF) + lane;
  const int4v* w2f = (const int4v*)(ldsb + W2F_OFF) + lane;

  #pragma unroll 1
  for (int s = 0; s < 50; s++) {
    const float dt = dtf[s];
    const float m2dt = -2.0f * dt;

    // ---- state -> 4 B-frags (pure register packing) ----
    FB hb[4];
    #pragma unroll
    for (int kc = 0; kc < 4; kc++)
      hb[kc].i = packfrag(h4[2 * kc], h4[2 * kc + 1]);

    // ---- 8 hid-pairs (32 hid each): mm1 -> tanh -> mm2 ----
    #pragma unroll 1
    for (int p = 0; p < 8; p++) {
      const int nt0 = 2 * p, nt1 = 2 * p + 1;
      FB wA[4], wB[4];
      #pragma unroll
      for (int c = 0; c < 4; c++) {
        wA[c].i = w1f[(nt0 * 4 + c) * 64];
        wB[c].i = w1f[(nt1 * 4 + c) * 64];
      }
      // g init = b1 (pre-scaled), two independent 4-chains
      float4v g0 = *(const float4v*)&b1f[nt0 * 16 + q * 4];
      float4v g1 = *(const float4v*)&b1f[nt1 * 16 + q * 4];
      #pragma unroll
      for (int c = 0; c < 4; c++) {
        g0 = MFMA16(wA[c].s, hb[c].s, g0);
        g1 = MFMA16(wB[c].s, hb[c].s, g1);
      }

      // W2 frags for this 32-K chunk (issued before tanh)
      FB w2r[8];
      #pragma unroll
      for (int tb = 0; tb < 8; tb++)
        w2r[tb].i = w2f[(p * 8 + tb) * 64];

      // act = dt*tanh: a = dt - 2dt * rcp(exp2(g) + 1)   [g pre-scaled]
      float4v a0, a1;
      #pragma unroll
      for (int r = 0; r < 4; r++) {
        a0[r] = fmaf(__builtin_amdgcn_rcpf(__builtin_amdgcn_exp2f(g0[r]) + 1.0f), m2dt, dt);
        a1[r] = fmaf(__builtin_amdgcn_rcpf(__builtin_amdgcn_exp2f(g1[r]) + 1.0f), m2dt, dt);
      }
      FB af;
      af.i = packfrag(a0, a1);

      // mm2: h += act-chunk @ W2-chunk (8 independent accumulator chains)
      #pragma unroll
      for (int tb = 0; tb < 8; tb++)
        h4[tb] = MFMA16(w2r[tb].s, af.s, h4[tb]);
    }

    // ---- h += dt * b2 ----
    #pragma unroll
    for (int tb = 0; tb < 8; tb++)
      #pragma unroll
      for (int r = 0; r < 4; r++)
        h4[tb][r] = fmaf(dt, b2v[tb][r], h4[tb][r]);
  }

  // ---- store ----
  #pragma unroll
  for (int tb = 0; tb < 8; tb++)
    *(float4v*)&out[row * 128 + tb * 16 + q * 4] = h4[tb];
}

extern "C" void kernel_launch(void* const* d_in, const int* in_sizes, int n_in,
                              void* d_out, int out_size, void* d_ws, size_t ws_size,
                              hipStream_t stream) {
  const float* inp = (const float*)d_in[0];
  const float* ts  = (const float*)d_in[1];
  const float* W1  = (const float*)d_in[2];
  const float* b1  = (const float*)d_in[3];
  const float* W2  = (const float*)d_in[4];
  const float* b2  = (const float*)d_in[5];
  hipLaunchKernelGGL(ode_kernel, dim3(256), dim3(512), 0, stream,
                     inp, ts, W1, b1, W2, b2, (float*)d_out);
}